// Round 12
// baseline (93.682 us; speedup 1.0000x reference)
//
#include <hip/hip_runtime.h>

// ---- types -----------------------------------------------------------------
typedef __bf16 bf16;
typedef __attribute__((ext_vector_type(8))) __bf16 bf16x8;
typedef __attribute__((ext_vector_type(4))) __bf16 bf16x4;
typedef __attribute__((ext_vector_type(4))) float  f32x4;

static __device__ __forceinline__ f32x4 mfma16(bf16x8 a, bf16x8 b, f32x4 c) {
  return __builtin_amdgcn_mfma_f32_16x16x32_bf16(a, b, c, 0, 0, 0);
}
static __device__ __forceinline__ float fexp2(float x) {
  return __builtin_amdgcn_exp2f(x);
}
static __device__ __forceinline__ float flog2(float x) {
  return __builtin_amdgcn_logf(x);
}

// exp(s/sqrt(128)) = exp2(s * C1). C1 folded into Wq/bq at prep time.
#define EXP_C1 (1.4426950408889634f / 11.313708498984760f)

// async global->LDS, 16B/lane; dst base is wave-uniform, HW adds lane*16.
typedef const __attribute__((address_space(1))) unsigned int gas_u32;
typedef __attribute__((address_space(3))) unsigned int las_u32;
#define GLDS16(gp, lp) __builtin_amdgcn_global_load_lds((gas_u32*)(gp), (las_u32*)(lp), 16, 0, 0)

// RACE FIX (keep): drain own vmcnt BEFORE s_barrier so cross-wave DMA
// completion is guaranteed.
#define WAITN0() __asm__ volatile("s_waitcnt vmcnt(0)" ::: "memory")

// Granule-major tile (128 rows x 128 cols bf16, 32KB): elem(r,c) = (c>>3)*1024 + r*8 + (c&7).
// V is ROW-PERMUTED (k_qkv epilogue) so the PV MFMA consumes the QK^T
// C-fragment from registers: slot (quad,e) of 32-block s holds V row
// k = 32s + quad*4 + (e&3) + 16*(e>>2).
//
// XCD SWIZZLE: k_stats/k_attn grids are (64 b, 8 qt) with b on X. Same-b
// blocks have linear ids stride 64 (== 0 mod 8 XCDs) -> same XCD L2.
//
// r17->r18: k_qkv rebuilt around ZERO-REGISTER staging. Every register-based
// pipeline attempt (r12-r15) died in the allocator (VGPR pinned 64/128,
// 60-240MB scratch). Now: global_load_lds stages raw fp32 q (64-row tile =
// 64KB, dbuf 2x64KB, 1 block/CU, 512thr, bounds(512,2) -> 256-VGPR cap);
// fp32->bf16 conversion moved into the fragment path (VALU was 10% idle);
// QKV fused (one ax read feeds 3 projections). LDS rows are 1024B == 0
// mod 128 -> XOR swizzle byte^=(row&7)<<4 applied on the GLOBAL source
// (GLDS dst must stay linear, m173) and on reads -> even bank spread.
// Per iter: WAITN0 -> barrier -> STAGE(t+1) -> compute(t): next tile's
// 64KB streams under compute; HBM stays busy through the wait.
// Pre-committed failure: VGPR=64 or WRITE>>48MB -> spill again -> revert.

// ============================================================================
// Kernel 0: prep. W[3][128][256] fp32 -> Wc[3][32 g][128 n][8] bf16.
// Wq additionally scaled by C1. Also initializes out[8192] = -inf for the
// k_attn atomic-max epilogue.
// ============================================================================
__global__ __launch_bounds__(256) void k_prep(
    const float* __restrict__ Wq, const float* __restrict__ Wk,
    const float* __restrict__ Wv, bf16* __restrict__ Wc, float* __restrict__ out)
{
  int id = blockIdx.x * 256 + threadIdx.x;      // 48 blocks = 3*4096
  if (id < 8192) out[id] = -__builtin_inff();
  int proj = id >> 12, r = id & 4095;
  int g = r >> 7, n = r & 127;
  const float* W = proj == 0 ? Wq : proj == 1 ? Wk : Wv;
  const float sc = (proj == 0) ? EXP_C1 : 1.0f;
  const float4* src = (const float4*)(W + n * 256 + g * 8);
  float4 a = src[0], b = src[1];
  bf16x8 o = { (bf16)(a.x * sc), (bf16)(a.y * sc), (bf16)(a.z * sc), (bf16)(a.w * sc),
               (bf16)(b.x * sc), (bf16)(b.y * sc), (bf16)(b.z * sc), (bf16)(b.w * sc) };
  *(bf16x8*)(Wc + (size_t)proj * 32768 + g * 1024 + n * 8) = o;
}

// ============================================================================
// Kernel 1: QKV projection, async-staged + fused. grid(256), block 512
// (8 waves as 2 row-halves x 4 col-groups), 1 block/CU, 4 tiles of 64 rows
// per block. Stage = GLDS16 of raw fp32 (zero registers), dbuf 2x64KB.
// fp32->bf16 conversion in the fragment path; one ax read feeds Q,K,V.
// ============================================================================
__global__ __launch_bounds__(512, 2) void k_qkv(
    const float* __restrict__ q, const bf16* __restrict__ Wc,
    const float* __restrict__ bq, const float* __restrict__ bk, const float* __restrict__ bv,
    bf16* __restrict__ Qb, bf16* __restrict__ Kb, bf16* __restrict__ VT)
{
  __shared__ char Alf[2][65536];                // fp32 64-row tiles, dbuf

  const int tid = threadIdx.x, lane = tid & 63, wave = tid >> 6;
  const int ln = lane & 15, quad = lane >> 4;
  const int wr = wave >> 2, wc = wave & 3;      // 2x4 waves: 32 rows x 32 cols
  const int tile0 = blockIdx.x * 4;

  // Stage tile (64 rows x 256 f32 = 64KB): chunk ch = one row (1KB).
  // Global source pre-swizzled (byte ^ (row&7)<<4) so reads can unswizzle;
  // LDS destination stays linear (GLDS16 requirement).
#define STAGE(bi, tile) do {                                                     \
    const char* src_ = (const char*)(q + (size_t)(tile) * 16384);                \
    char* d_ = Alf[bi];                                                          \
    for (int c = 0; c < 8; ++c) {                                                \
      int ch = wave * 8 + c;                                                     \
      GLDS16(src_ + ch * 1024 + ((lane * 16) ^ ((ch & 7) << 4)),                 \
             d_ + ch * 1024);                                                    \
    }                                                                            \
  } while (0)

  STAGE(0, tile0);

  for (int it = 0; it < 4; ++it) {
    WAITN0();
    __syncthreads();                            // tile it staged, prev reads done
    if (it < 3) STAGE((it + 1) & 1, tile0 + it + 1);
    const char* Bf = Alf[it & 1];

    const int m0 = (tile0 + it) * 64;
    const int b = m0 >> 10, st = (m0 & 1023) >> 7, s_off = m0 & 64;
    const size_t tbase = ((size_t)b * 8 + st) * 16384;

    f32x4 aQ[2][2] = {}, aK[2][2] = {}, aV[2][2] = {};
    for (int kk = 0; kk < 8; ++kk) {
      int g = kk * 4 + quad;
      bf16x8 ax[2];
      for (int t = 0; t < 2; ++t) {
        int r = wr * 32 + t * 16 + ln;
        int cb = g * 32, sw = (r & 7) << 4;
        f32x4 a0 = *(const f32x4*)(Bf + r * 1024 + (cb ^ sw));
        f32x4 a1 = *(const f32x4*)(Bf + r * 1024 + ((cb + 16) ^ sw));
        ax[t] = bf16x8{ (bf16)a0[0], (bf16)a0[1], (bf16)a0[2], (bf16)a0[3],
                        (bf16)a1[0], (bf16)a1[1], (bf16)a1[2], (bf16)a1[3] };
      }
      bf16x8 bwQ[2], bwK[2], bwV[2];
      for (int t2 = 0; t2 < 2; ++t2) {
        const int off = g * 1024 + (wc * 32 + t2 * 16 + ln) * 8;
        bwQ[t2] = *(const bf16x8*)(Wc + off);
        bwK[t2] = *(const bf16x8*)(Wc + 32768 + off);
        bwV[t2] = *(const bf16x8*)(Wc + 65536 + off);
      }
      __builtin_amdgcn_s_setprio(1);
      for (int i = 0; i < 2; ++i)
        for (int j = 0; j < 2; ++j) {
          aQ[i][j] = mfma16(bwQ[i], ax[j], aQ[i][j]);   // D[d][s]
          aK[i][j] = mfma16(bwK[i], ax[j], aK[i][j]);
        }
      for (int i = 0; i < 2; ++i)
        for (int j = 0; j < 2; ++j)
          aV[i][j] = mfma16(ax[i], bwV[j], aV[i][j]);   // D[s][d]
      __builtin_amdgcn_s_setprio(0);
    }

    // Q,K epilogue: granule-major [s][d]; regs = 4 consecutive d -> bf16x4
    for (int p = 0; p < 2; ++p) {
      bf16* dst = (p == 0 ? Qb : Kb) + tbase;
      const float* bias = p == 0 ? bq : bk;
      for (int i = 0; i < 2; ++i) {
        float4 b4 = *(const float4*)&bias[wc * 32 + i * 16 + quad * 4];
        if (p == 0) { b4.x *= EXP_C1; b4.y *= EXP_C1; b4.z *= EXP_C1; b4.w *= EXP_C1; }
        int gd = wc * 4 + i * 2 + (quad >> 1);  // d-granule
        int e0 = (quad & 1) * 4;
        for (int j = 0; j < 2; ++j) {
          int s = s_off + wr * 32 + j * 16 + ln;
          const f32x4 a_ = p == 0 ? aQ[i][j] : aK[i][j];
          bf16x4 o = { (bf16)(a_[0] + b4.x), (bf16)(a_[1] + b4.y),
                       (bf16)(a_[2] + b4.z), (bf16)(a_[3] + b4.w) };
          *(bf16x4*)&dst[(size_t)gd * 1024 + (size_t)s * 8 + e0] = o;
        }
      }
    }
    { // V epilogue: [s-granule][d][8], ROW-PERMUTED
      bf16* dst = VT + tbase;
      for (int j = 0; j < 2; ++j) {
        int d = wc * 32 + j * 16 + ln;
        float bb = bv[d];
        for (int i = 0; i < 2; ++i) {
          int s0 = s_off + wr * 32 + i * 16 + quad * 4;
          int G  = (s0 >> 5) * 4 + ((s0 & 15) >> 2);
          int e0 = (s0 & 16) >> 2;
          bf16x4 o = { (bf16)(aV[i][j][0] + bb), (bf16)(aV[i][j][1] + bb),
                       (bf16)(aV[i][j][2] + bb), (bf16)(aV[i][j][3] + bb) };
          *(bf16x4*)&dst[(size_t)G * 1024 + (size_t)d * 8 + e0] = o;
        }
      }
    }
  }
#undef STAGE
}

// ============================================================================
// Kernel 2: column stats. grid(64 b, 8 kt), block 256, 2 blocks/CU.
// K-frags register-resident; Q streamed via double-buffered DMA.
// Writes nlg[k] = -log2(colsum) (consumed as QK accumulator init in k_attn).
// ============================================================================
__global__ __launch_bounds__(256, 2) void k_stats(
    const bf16* __restrict__ Qb, const bf16* __restrict__ Kb, float* __restrict__ nlg)
{
  __shared__ char Qbuf[2][32768];
  const int b = blockIdx.x, kt = blockIdx.y;
  const int tid = threadIdx.x, lane = tid & 63, wave = tid >> 6;
  const int ln = lane & 15, quad = lane >> 4;

  const bf16* ktile = Kb + ((size_t)b * 8 + kt) * 16384;
  bf16x8 ak[2][4];                              // wave's 32 k-rows, full d=128
  for (int i = 0; i < 2; ++i)
    for (int kk = 0; kk < 4; ++kk)
      ak[i][kk] = *(const bf16x8*)(ktile + (kk * 4 + quad) * 1024 + (wave * 32 + i * 16 + ln) * 8);

  const char* qb_b = (const char*)(Qb + (size_t)b * 8 * 16384);
  for (int c = 0; c < 8; ++c)                   // prologue DMA q-tile 0
    GLDS16(qb_b + (wave * 8 + c) * 1024 + lane * 16, &Qbuf[0][(wave * 8 + c) * 1024]);

  f32x4 csum[2] = {};
  for (int qt = 0; qt < 8; ++qt) {
    WAITN0();
    __syncthreads();                            // all waves' DMA(qt) complete
    if (qt < 7)
      for (int c = 0; c < 8; ++c)
        GLDS16(qb_b + (size_t)(qt + 1) * 32768 + (wave * 8 + c) * 1024 + lane * 16,
               &Qbuf[(qt + 1) & 1][(wave * 8 + c) * 1024]);
    const char* Ql = Qbuf[qt & 1];
    for (int jq = 0; jq < 8; ++jq) {
      f32x4 s0 = {}, s1 = {};
      __builtin_amdgcn_s_setprio(1);
      for (int kk = 0; kk < 4; ++kk) {
        bf16x8 bqf = *(const bf16x8*)(Ql + ((kk * 4 + quad) * 2 + (jq >> 2)) * 1024
                                         + ((jq * 16 + ln) & 63) * 16);
        s0 = mfma16(ak[0][kk], bqf, s0);
        s1 = mfma16(ak[1][kk], bqf, s1);
      }
      __builtin_amdgcn_s_setprio(0);
      for (int rr = 0; rr < 4; ++rr) {
        csum[0][rr] += fexp2(s0[rr]);           // Q pre-scaled by C1
        csum[1][rr] += fexp2(s1[rr]);
      }
    }
  }
  for (int i = 0; i < 2; ++i)
    for (int rr = 0; rr < 4; ++rr) {
      float v = csum[i][rr];
      v += __shfl_xor(v, 1, 64); v += __shfl_xor(v, 2, 64);
      v += __shfl_xor(v, 4, 64); v += __shfl_xor(v, 8, 64);
      csum[i][rr] = v;
    }
  if (ln == 0) {
    float* dst = nlg + (size_t)b * 1024 + kt * 128 + wave * 32 + quad * 4;
    for (int i = 0; i < 2; ++i)
      for (int rr = 0; rr < 4; ++rr)
        dst[i * 16 + rr] = -flog2(csum[i][rr]);
  }
}

// ============================================================================
// Kernel 3: fused attention, QK software-pipelined one tile ahead.
// grid(64 b, 8 qt), block 256 (4 waves x 32q), 2 blocks/CU.
// bufK/bufV dbuf-2 (K prefetch 2 ahead, V 1 ahead); sacc ping-pong sA/sB.
// Per iter: wait+barrier, issue K(t+2)/V(t+1), QK(t+1) || exp(t), PV(t).
// ============================================================================
__global__ __launch_bounds__(256, 2) void k_attn(
    const bf16* __restrict__ Qb, const bf16* __restrict__ Kb, const bf16* __restrict__ VT,
    const float* __restrict__ nlg, float* __restrict__ out)
{
  __shared__ char bufK[2][16384];
  __shared__ char bufV[2][16384];
  __shared__ float nll[1024];
  __shared__ float redm[4][128];

  const int b = blockIdx.x, qt = blockIdx.y;
  const int tid = threadIdx.x, lane = tid & 63, wave = tid >> 6;
  const int ln = lane & 15, quad = lane >> 4;

  *(float4*)&nll[tid * 4] = *(const float4*)(nlg + (size_t)b * 1024 + tid * 4);

  const bf16* qtile = Qb + ((size_t)b * 8 + qt) * 16384;
  bf16x8 bq_[2][4];                             // wave's 32 q-rows, full d
  for (int j = 0; j < 2; ++j)
    for (int kk = 0; kk < 4; ++kk)
      bq_[j][kk] = *(const bf16x8*)(qtile + (kk * 4 + quad) * 1024 + (wave * 32 + j * 16 + ln) * 8);

  const char* kb_b = (const char*)(Kb + (size_t)b * 8 * 16384);
  const char* vt_b = (const char*)(VT + (size_t)b * 8 * 16384);

#define K_DMA(t) do {                                                            \
    const char* ksrc = kb_b + (size_t)((t) >> 1) * 32768 + ((t) & 1) * 1024;     \
    char* dk = bufK[(t) & 1];                                                    \
    for (int c = 0; c < 4; ++c) {                                                \
      int ch = wave * 4 + c;                                                     \
      GLDS16(ksrc + ch * 2048 + lane * 16, dk + ch * 1024);                      \
    }                                                                            \
  } while (0)
#define V_DMA(t) do {                                                            \
    const char* vsrc = vt_b + (size_t)((t) >> 1) * 32768 + ((t) & 1) * 16384;    \
    char* dv = bufV[(t) & 1];                                                    \
    for (int c = 0; c < 4; ++c) {                                                \
      int ch = wave * 4 + c;                                                     \
      GLDS16(vsrc + (ch >> 1) * 2048 + (ch & 1) * 1024 + lane * 16,              \
             dv + ch * 1024);                                                    \
    }                                                                            \
  } while (0)

  // QK for tile tt into SN (C-init = -log2 colsum; row rr of frag i is
  // k = tt*64 + i*16 + quad*4 + rr).
#define QK(tt, SN) do {                                                          \
    const char* Kl = bufK[(tt) & 1];                                             \
    _Pragma("unroll")                                                            \
    for (int i = 0; i < 4; ++i) {                                                \
      float4 L4 = *(float4*)&nll[(tt) * 64 + i * 16 + quad * 4];                 \
      f32x4 ini = { L4.x, L4.y, L4.z, L4.w };                                    \
      SN[i][0] = ini; SN[i][1] = ini;                                            \
    }                                                                            \
    __builtin_amdgcn_s_setprio(1);                                               \
    _Pragma("unroll")                                                            \
    for (int kk = 0; kk < 4; ++kk) {                                             \
      bf16x8 ak[4];                                                              \
      _Pragma("unroll")                                                          \
      for (int i = 0; i < 4; ++i)                                                \
        ak[i] = *(const bf16x8*)(Kl + (kk * 4 + quad) * 1024 + (i * 16 + ln) * 16); \
      _Pragma("unroll")                                                          \
      for (int i = 0; i < 4; ++i) {                                              \
        SN[i][0] = mfma16(ak[i], bq_[0][kk], SN[i][0]);                          \
        SN[i][1] = mfma16(ak[i], bq_[1][kk], SN[i][1]);                          \
      }                                                                          \
    }                                                                            \
    __builtin_amdgcn_s_setprio(0);                                               \
  } while (0)

  // exp + PV for tile tt from SC (interleaved per 32-k half).
#define EXPPV(tt, SC) do {                                                       \
    const char* Vl = bufV[(tt) & 1];                                             \
    _Pragma("unroll")                                                            \
    for (int s = 0; s < 2; ++s) {                                                \
      f32x4 lo0 = SC[2 * s][0], hi0 = SC[2 * s + 1][0];                          \
      f32x4 lo1 = SC[2 * s][1], hi1 = SC[2 * s + 1][1];                          \
      bf16x8 pf0 = bf16x8{                                                       \
        (bf16)fexp2(lo0[0]), (bf16)fexp2(lo0[1]), (bf16)fexp2(lo0[2]), (bf16)fexp2(lo0[3]), \
        (bf16)fexp2(hi0[0]), (bf16)fexp2(hi0[1]), (bf16)fexp2(hi0[2]), (bf16)fexp2(hi0[3]) }; \
      bf16x8 pf1 = bf16x8{                                                       \
        (bf16)fexp2(lo1[0]), (bf16)fexp2(lo1[1]), (bf16)fexp2(lo1[2]), (bf16)fexp2(lo1[3]), \
        (bf16)fexp2(hi1[0]), (bf16)fexp2(hi1[1]), (bf16)fexp2(hi1[2]), (bf16)fexp2(hi1[3]) }; \
      _Pragma("unroll")                                                          \
      for (int j2 = 0; j2 < 8; ++j2) {                                           \
        bf16x8 bv_ = *(const bf16x8*)(Vl + ((s * 4 + quad) * 2 + (j2 >> 2)) * 1024 \
                                         + ((j2 * 16 + ln) & 63) * 16);          \
        oacc[0][j2] = mfma16(pf0, bv_, oacc[0][j2]);                             \
        oacc[1][j2] = mfma16(pf1, bv_, oacc[1][j2]);                             \
      }                                                                          \
    }                                                                            \
  } while (0)

  // One pipelined step: tile t uses CUR sacc; QK(t+1) fills NXT.
#define STEP(t, CUR, NXT) do {                                                   \
    WAITN0();                                                                    \
    __syncthreads();                                                             \
    if ((t) < 14) K_DMA((t) + 2);                                                \
    if ((t) < 15) V_DMA((t) + 1);                                                \
    if ((t) < 15) QK((t) + 1, NXT);                                              \
    EXPPV((t), CUR);                                                             \
  } while (0)

  f32x4 oacc[2][8] = {};
  f32x4 sA[4][2], sB[4][2];

  K_DMA(0);
  WAITN0();
  __syncthreads();                              // K(0) visible to all waves
  K_DMA(1); V_DMA(0);                           // land during QK(0)
  QK(0, sA);

  for (int tp = 0; tp < 8; ++tp) {
    STEP(2 * tp,     sA, sB);
    STEP(2 * tp + 1, sB, sA);
  }
#undef STEP
#undef EXPPV
#undef QK
#undef K_DMA
#undef V_DMA

  // max over this block's 128 q rows, per output column d
  for (int j2 = 0; j2 < 8; ++j2) {
    float m = -3.4e38f;
    for (int j = 0; j < 2; ++j)
      for (int rr = 0; rr < 4; ++rr)
        m = fmaxf(m, oacc[j][j2][rr]);
    m = fmaxf(m, __shfl_xor(m, 16, 64));
    m = fmaxf(m, __shfl_xor(m, 32, 64));
    if (lane < 16) redm[wave][j2 * 16 + ln] = m;
  }
  __syncthreads();
  if (tid < 128) {
    float m = fmaxf(fmaxf(redm[0][tid], redm[1][tid]), fmaxf(redm[2][tid], redm[3][tid]));
    // sign-aware integer atomic max (IEEE total order); out pre-init'd to -inf
    float* addr = out + (size_t)b * 128 + tid;
    if (m >= 0.0f) atomicMax((int*)addr, __float_as_int(m));
    else           atomicMin((unsigned int*)addr, __float_as_uint(m));
  }
}

// ============================================================================
extern "C" void kernel_launch(void* const* d_in, const int* in_sizes, int n_in,
                              void* d_out, int out_size, void* d_ws, size_t ws_size,
                              hipStream_t stream) {
  const float* q  = (const float*)d_in[0];
  const float* Wq = (const float*)d_in[1];
  const float* bq = (const float*)d_in[2];
  const float* Wk = (const float*)d_in[3];
  const float* bk = (const float*)d_in[4];
  const float* Wv = (const float*)d_in[5];
  const float* bv = (const float*)d_in[6];
  float* out = (float*)d_out;

  char* ws = (char*)d_ws;
  bf16*  Qb    = (bf16*)(ws);                         // 16 MB granule tiles [s][d]
  bf16*  Kb    = (bf16*)(ws + (16u << 20));           // 16 MB
  bf16*  VT    = (bf16*)(ws + (32u << 20));           // 16 MB (V^T, row-permuted)
  float* nlg   = (float*)(ws + (48u << 20));          // 256 KB [64][1024]  -log2(colsum)
  bf16*  Wc    = (bf16*)(ws + (49u << 20));           // 192 KB [3][32][128][8]

  k_prep <<<48,           256, 0, stream>>>(Wq, Wk, Wv, Wc, out);
  k_qkv  <<<dim3(256),    512, 0, stream>>>(q, Wc, bq, bk, bv, Qb, Kb, VT);
  k_stats<<<dim3(64, 8),  256, 0, stream>>>(Qb, Kb, nlg);
  k_attn <<<dim3(64, 8),  256, 0, stream>>>(Qb, Kb, VT, nlg, out);
}

// Round 13
// 86.347 us; speedup vs baseline: 1.0849x; 1.0849x over previous
//
#include <hip/hip_runtime.h>

// ---- types -----------------------------------------------------------------
typedef __bf16 bf16;
typedef __attribute__((ext_vector_type(8))) __bf16 bf16x8;
typedef __attribute__((ext_vector_type(4))) __bf16 bf16x4;
typedef __attribute__((ext_vector_type(4))) float  f32x4;

static __device__ __forceinline__ f32x4 mfma16(bf16x8 a, bf16x8 b, f32x4 c) {
  return __builtin_amdgcn_mfma_f32_16x16x32_bf16(a, b, c, 0, 0, 0);
}
static __device__ __forceinline__ float fexp2(float x) {
  return __builtin_amdgcn_exp2f(x);
}
static __device__ __forceinline__ float flog2(float x) {
  return __builtin_amdgcn_logf(x);
}

// exp(s/sqrt(128)) = exp2(s * C1). C1 folded into Wq/bq at prep time.
#define EXP_C1 (1.4426950408889634f / 11.313708498984760f)

// async global->LDS, 16B/lane; dst base is wave-uniform, HW adds lane*16.
typedef const __attribute__((address_space(1))) unsigned int gas_u32;
typedef __attribute__((address_space(3))) unsigned int las_u32;
#define GLDS16(gp, lp) __builtin_amdgcn_global_load_lds((gas_u32*)(gp), (las_u32*)(lp), 16, 0, 0)

// RACE FIX (keep): drain own vmcnt BEFORE s_barrier so cross-wave DMA
// completion is guaranteed.
#define WAITN0() __asm__ volatile("s_waitcnt vmcnt(0)" ::: "memory")

// Granule-major tile (128 rows x 128 cols bf16, 32KB): elem(r,c) = (c>>3)*1024 + r*8 + (c&7).
// V is ROW-PERMUTED (k_qkv epilogue) so the PV MFMA consumes the QK^T
// C-fragment from registers: slot (quad,e) of 32-block s holds V row
// k = 32s + quad*4 + (e&3) + 16*(e>>2).
//
// XCD SWIZZLE: k_stats/k_attn grids are (64 b, 8 qt) with b on X. Same-b
// blocks have linear ids stride 64 (== 0 mod 8 XCDs) -> same XCD L2.
//
// r18->r19 post-mortem: r18's zero-register staging was mechanically clean
// (VGPR 116, no scratch traffic) yet k_qkv stayed 40us and total regressed
// -> staging convoy is NOT the binder; reverted. Cycle budget points at
// W-fragment L2 latency (~160-200cy exposed per kk, only ~40cy MFMA cover).
// r14's depth-4 prefetch targeted this but its 64 extra VGPR pushed past
// the 128 cap (silent spill, WRITE 88-190MB). r19: depth-2 prefetch =
// 16 extra VGPR (~75-90 total), safely under cap. Spill signature to
// watch: VGPR pinned at 64 / WRITE >> 49MB.

// ============================================================================
// Kernel 0: prep. W[3][128][256] fp32 -> Wc[3][32 g][128 n][8] bf16.
// Wq additionally scaled by C1. Also initializes out[8192] = -inf for the
// k_attn atomic-max epilogue.
// ============================================================================
__global__ __launch_bounds__(256) void k_prep(
    const float* __restrict__ Wq, const float* __restrict__ Wk,
    const float* __restrict__ Wv, bf16* __restrict__ Wc, float* __restrict__ out)
{
  int id = blockIdx.x * 256 + threadIdx.x;      // 48 blocks = 3*4096
  if (id < 8192) out[id] = -__builtin_inff();
  int proj = id >> 12, r = id & 4095;
  int g = r >> 7, n = r & 127;
  const float* W = proj == 0 ? Wq : proj == 1 ? Wk : Wv;
  const float sc = (proj == 0) ? EXP_C1 : 1.0f;
  const float4* src = (const float4*)(W + n * 256 + g * 8);
  float4 a = src[0], b = src[1];
  bf16x8 o = { (bf16)(a.x * sc), (bf16)(a.y * sc), (bf16)(a.z * sc), (bf16)(a.w * sc),
               (bf16)(b.x * sc), (bf16)(b.y * sc), (bf16)(b.z * sc), (bf16)(b.w * sc) };
  *(bf16x8*)(Wc + (size_t)proj * 32768 + g * 1024 + n * 8) = o;
}

// ============================================================================
// Kernel 1: QKV projection. grid(1024), block 256, 4 blocks/CU.
// r16 body (stride 520) + r19 depth-2 W register prefetch (16 VGPR).
// ============================================================================
__global__ __launch_bounds__(256, 4) void k_qkv(
    const float* __restrict__ q, const bf16* __restrict__ Wc,
    const float* __restrict__ bq, const float* __restrict__ bk, const float* __restrict__ bv,
    bf16* __restrict__ Qb, bf16* __restrict__ Kb, bf16* __restrict__ VT)
{
  __shared__ bf16 Al[32 * 520];   // 32 x-granule chunks (64 rows), stride 520 elems

  const int tid = threadIdx.x, lane = tid & 63, wave = tid >> 6;
  const int ln = lane & 15, quad = lane >> 4;
  const int wc = wave;                          // 1x4 waves: 64 rows x 32 cols
  const int m0 = blockIdx.x * 64;

  { // stage A: coalesced float4 -> bf16 chunks
    const float* src = q + (size_t)m0 * 256;
    for (int it = 0; it < 16; ++it) {
      int f = it * 1024 + tid * 4;
      int r = f >> 8, c = f & 255;
      float4 v = *(const float4*)(src + f);
      bf16x4 o = { (bf16)v.x, (bf16)v.y, (bf16)v.z, (bf16)v.w };
      *(bf16x4*)&Al[(c >> 3) * 520 + r * 8 + (c & 7)] = o;
    }
  }
  __syncthreads();

  const int b = m0 >> 10, st = (m0 & 1023) >> 7, s_off = m0 & 64;
  const size_t tbase = ((size_t)b * 8 + st) * 16384;

#define BW_LOAD(slot, kkv) do {                                                               \
    bwp[slot][0] = *(const bf16x8*)(W + ((kkv) * 4 + quad) * 1024 + (wc * 32 + ln) * 8);      \
    bwp[slot][1] = *(const bf16x8*)(W + ((kkv) * 4 + quad) * 1024 + (wc * 32 + 16 + ln) * 8); \
  } while (0)

  for (int p = 0; p < 3; ++p) {
    const bf16* W = Wc + (size_t)p * 32768;
    const float* bias = p == 0 ? bq : p == 1 ? bk : bv;
    bf16x8 bwp[2][2];                           // depth-2 W pipeline (16 VGPR)
    BW_LOAD(0, 0);

    if (p < 2) {   // D[d][s]: A=W (m=d), B=X (n=s)
      f32x4 acc[2][4] = {};
      #pragma unroll
      for (int kk = 0; kk < 8; ++kk) {
        int g = kk * 4 + quad;
        bf16x8 ax[4];
        #pragma unroll
        for (int t = 0; t < 4; ++t)
          ax[t] = *(const bf16x8*)&Al[g * 520 + (t * 16 + ln) * 8];
        if (kk < 7) BW_LOAD((kk + 1) & 1, kk + 1);   // prefetch kk+1 under MFMAs
        bf16x8 b0 = bwp[kk & 1][0], b1 = bwp[kk & 1][1];
        #pragma unroll
        for (int j = 0; j < 4; ++j) {
          acc[0][j] = mfma16(b0, ax[j], acc[0][j]);
          acc[1][j] = mfma16(b1, ax[j], acc[1][j]);
        }
      }
      bf16* dst = (p == 0 ? Qb : Kb) + tbase;
      for (int i = 0; i < 2; ++i) {
        float4 b4 = *(const float4*)&bias[wc * 32 + i * 16 + quad * 4];
        if (p == 0) { b4.x *= EXP_C1; b4.y *= EXP_C1; b4.z *= EXP_C1; b4.w *= EXP_C1; }
        int gd = wc * 4 + i * 2 + (quad >> 1);    // d-granule
        int e0 = (quad & 1) * 4;
        for (int j = 0; j < 4; ++j) {
          int s = s_off + j * 16 + ln;
          bf16x4 o = { (bf16)(acc[i][j][0] + b4.x), (bf16)(acc[i][j][1] + b4.y),
                       (bf16)(acc[i][j][2] + b4.z), (bf16)(acc[i][j][3] + b4.w) };
          *(bf16x4*)&dst[(size_t)gd * 1024 + (size_t)s * 8 + e0] = o;
        }
      }
    } else {       // D[s][d]: A=X (m=s), B=W (n=d)
      f32x4 acc[4][2] = {};
      #pragma unroll
      for (int kk = 0; kk < 8; ++kk) {
        int g = kk * 4 + quad;
        bf16x8 ax[4];
        #pragma unroll
        for (int t = 0; t < 4; ++t)
          ax[t] = *(const bf16x8*)&Al[g * 520 + (t * 16 + ln) * 8];
        if (kk < 7) BW_LOAD((kk + 1) & 1, kk + 1);
        bf16x8 b0 = bwp[kk & 1][0], b1 = bwp[kk & 1][1];
        #pragma unroll
        for (int i = 0; i < 4; ++i) {
          acc[i][0] = mfma16(ax[i], b0, acc[i][0]);
          acc[i][1] = mfma16(ax[i], b1, acc[i][1]);
        }
      }
      bf16* dst = VT + tbase;   // V: [s-granule][d][8], ROW-PERMUTED
      for (int j = 0; j < 2; ++j) {
        int d = wc * 32 + j * 16 + ln;
        float bb = bias[d];
        for (int i = 0; i < 4; ++i) {
          int s0 = s_off + i * 16 + quad * 4;
          int G  = (s0 >> 5) * 4 + ((s0 & 15) >> 2);
          int e0 = (s0 & 16) >> 2;
          bf16x4 o = { (bf16)(acc[i][j][0] + bb), (bf16)(acc[i][j][1] + bb),
                       (bf16)(acc[i][j][2] + bb), (bf16)(acc[i][j][3] + bb) };
          *(bf16x4*)&dst[(size_t)G * 1024 + (size_t)d * 8 + e0] = o;
        }
      }
    }
  }
#undef BW_LOAD
}

// ============================================================================
// Kernel 2: column stats. grid(64 b, 8 kt), block 256, 2 blocks/CU.
// K-frags register-resident; Q streamed via double-buffered DMA.
// Writes nlg[k] = -log2(colsum) (consumed as QK accumulator init in k_attn).
// ============================================================================
__global__ __launch_bounds__(256, 2) void k_stats(
    const bf16* __restrict__ Qb, const bf16* __restrict__ Kb, float* __restrict__ nlg)
{
  __shared__ char Qbuf[2][32768];
  const int b = blockIdx.x, kt = blockIdx.y;
  const int tid = threadIdx.x, lane = tid & 63, wave = tid >> 6;
  const int ln = lane & 15, quad = lane >> 4;

  const bf16* ktile = Kb + ((size_t)b * 8 + kt) * 16384;
  bf16x8 ak[2][4];                              // wave's 32 k-rows, full d=128
  for (int i = 0; i < 2; ++i)
    for (int kk = 0; kk < 4; ++kk)
      ak[i][kk] = *(const bf16x8*)(ktile + (kk * 4 + quad) * 1024 + (wave * 32 + i * 16 + ln) * 8);

  const char* qb_b = (const char*)(Qb + (size_t)b * 8 * 16384);
  for (int c = 0; c < 8; ++c)                   // prologue DMA q-tile 0
    GLDS16(qb_b + (wave * 8 + c) * 1024 + lane * 16, &Qbuf[0][(wave * 8 + c) * 1024]);

  f32x4 csum[2] = {};
  for (int qt = 0; qt < 8; ++qt) {
    WAITN0();
    __syncthreads();                            // all waves' DMA(qt) complete
    if (qt < 7)
      for (int c = 0; c < 8; ++c)
        GLDS16(qb_b + (size_t)(qt + 1) * 32768 + (wave * 8 + c) * 1024 + lane * 16,
               &Qbuf[(qt + 1) & 1][(wave * 8 + c) * 1024]);
    const char* Ql = Qbuf[qt & 1];
    for (int jq = 0; jq < 8; ++jq) {
      f32x4 s0 = {}, s1 = {};
      __builtin_amdgcn_s_setprio(1);
      for (int kk = 0; kk < 4; ++kk) {
        bf16x8 bqf = *(const bf16x8*)(Ql + ((kk * 4 + quad) * 2 + (jq >> 2)) * 1024
                                         + ((jq * 16 + ln) & 63) * 16);
        s0 = mfma16(ak[0][kk], bqf, s0);
        s1 = mfma16(ak[1][kk], bqf, s1);
      }
      __builtin_amdgcn_s_setprio(0);
      for (int rr = 0; rr < 4; ++rr) {
        csum[0][rr] += fexp2(s0[rr]);           // Q pre-scaled by C1
        csum[1][rr] += fexp2(s1[rr]);
      }
    }
  }
  for (int i = 0; i < 2; ++i)
    for (int rr = 0; rr < 4; ++rr) {
      float v = csum[i][rr];
      v += __shfl_xor(v, 1, 64); v += __shfl_xor(v, 2, 64);
      v += __shfl_xor(v, 4, 64); v += __shfl_xor(v, 8, 64);
      csum[i][rr] = v;
    }
  if (ln == 0) {
    float* dst = nlg + (size_t)b * 1024 + kt * 128 + wave * 32 + quad * 4;
    for (int i = 0; i < 2; ++i)
      for (int rr = 0; rr < 4; ++rr)
        dst[i * 16 + rr] = -flog2(csum[i][rr]);
  }
}

// ============================================================================
// Kernel 3: fused attention, QK software-pipelined one tile ahead.
// grid(64 b, 8 qt), block 256 (4 waves x 32q), 2 blocks/CU.
// bufK/bufV dbuf-2 (K prefetch 2 ahead, V 1 ahead); sacc ping-pong sA/sB.
// Per iter: wait+barrier, issue K(t+2)/V(t+1), QK(t+1) || exp(t), PV(t).
// ============================================================================
__global__ __launch_bounds__(256, 2) void k_attn(
    const bf16* __restrict__ Qb, const bf16* __restrict__ Kb, const bf16* __restrict__ VT,
    const float* __restrict__ nlg, float* __restrict__ out)
{
  __shared__ char bufK[2][16384];
  __shared__ char bufV[2][16384];
  __shared__ float nll[1024];
  __shared__ float redm[4][128];

  const int b = blockIdx.x, qt = blockIdx.y;
  const int tid = threadIdx.x, lane = tid & 63, wave = tid >> 6;
  const int ln = lane & 15, quad = lane >> 4;

  *(float4*)&nll[tid * 4] = *(const float4*)(nlg + (size_t)b * 1024 + tid * 4);

  const bf16* qtile = Qb + ((size_t)b * 8 + qt) * 16384;
  bf16x8 bq_[2][4];                             // wave's 32 q-rows, full d
  for (int j = 0; j < 2; ++j)
    for (int kk = 0; kk < 4; ++kk)
      bq_[j][kk] = *(const bf16x8*)(qtile + (kk * 4 + quad) * 1024 + (wave * 32 + j * 16 + ln) * 8);

  const char* kb_b = (const char*)(Kb + (size_t)b * 8 * 16384);
  const char* vt_b = (const char*)(VT + (size_t)b * 8 * 16384);

#define K_DMA(t) do {                                                            \
    const char* ksrc = kb_b + (size_t)((t) >> 1) * 32768 + ((t) & 1) * 1024;     \
    char* dk = bufK[(t) & 1];                                                    \
    for (int c = 0; c < 4; ++c) {                                                \
      int ch = wave * 4 + c;                                                     \
      GLDS16(ksrc + ch * 2048 + lane * 16, dk + ch * 1024);                      \
    }                                                                            \
  } while (0)
#define V_DMA(t) do {                                                            \
    const char* vsrc = vt_b + (size_t)((t) >> 1) * 32768 + ((t) & 1) * 16384;    \
    char* dv = bufV[(t) & 1];                                                    \
    for (int c = 0; c < 4; ++c) {                                                \
      int ch = wave * 4 + c;                                                     \
      GLDS16(vsrc + (ch >> 1) * 2048 + (ch & 1) * 1024 + lane * 16,              \
             dv + ch * 1024);                                                    \
    }                                                                            \
  } while (0)

  // QK for tile tt into SN (C-init = -log2 colsum; row rr of frag i is
  // k = tt*64 + i*16 + quad*4 + rr).
#define QK(tt, SN) do {                                                          \
    const char* Kl = bufK[(tt) & 1];                                             \
    _Pragma("unroll")                                                            \
    for (int i = 0; i < 4; ++i) {                                                \
      float4 L4 = *(float4*)&nll[(tt) * 64 + i * 16 + quad * 4];                 \
      f32x4 ini = { L4.x, L4.y, L4.z, L4.w };                                    \
      SN[i][0] = ini; SN[i][1] = ini;                                            \
    }                                                                            \
    __builtin_amdgcn_s_setprio(1);                                               \
    _Pragma("unroll")                                                            \
    for (int kk = 0; kk < 4; ++kk) {                                             \
      bf16x8 ak[4];                                                              \
      _Pragma("unroll")                                                          \
      for (int i = 0; i < 4; ++i)                                                \
        ak[i] = *(const bf16x8*)(Kl + (kk * 4 + quad) * 1024 + (i * 16 + ln) * 16); \
      _Pragma("unroll")                                                          \
      for (int i = 0; i < 4; ++i) {                                              \
        SN[i][0] = mfma16(ak[i], bq_[0][kk], SN[i][0]);                          \
        SN[i][1] = mfma16(ak[i], bq_[1][kk], SN[i][1]);                          \
      }                                                                          \
    }                                                                            \
    __builtin_amdgcn_s_setprio(0);                                               \
  } while (0)

  // exp + PV for tile tt from SC (interleaved per 32-k half).
#define EXPPV(tt, SC) do {                                                       \
    const char* Vl = bufV[(tt) & 1];                                             \
    _Pragma("unroll")                                                            \
    for (int s = 0; s < 2; ++s) {                                                \
      f32x4 lo0 = SC[2 * s][0], hi0 = SC[2 * s + 1][0];                          \
      f32x4 lo1 = SC[2 * s][1], hi1 = SC[2 * s + 1][1];                          \
      bf16x8 pf0 = bf16x8{                                                       \
        (bf16)fexp2(lo0[0]), (bf16)fexp2(lo0[1]), (bf16)fexp2(lo0[2]), (bf16)fexp2(lo0[3]), \
        (bf16)fexp2(hi0[0]), (bf16)fexp2(hi0[1]), (bf16)fexp2(hi0[2]), (bf16)fexp2(hi0[3]) }; \
      bf16x8 pf1 = bf16x8{                                                       \
        (bf16)fexp2(lo1[0]), (bf16)fexp2(lo1[1]), (bf16)fexp2(lo1[2]), (bf16)fexp2(lo1[3]), \
        (bf16)fexp2(hi1[0]), (bf16)fexp2(hi1[1]), (bf16)fexp2(hi1[2]), (bf16)fexp2(hi1[3]) }; \
      _Pragma("unroll")                                                          \
      for (int j2 = 0; j2 < 8; ++j2) {                                           \
        bf16x8 bv_ = *(const bf16x8*)(Vl + ((s * 4 + quad) * 2 + (j2 >> 2)) * 1024 \
                                         + ((j2 * 16 + ln) & 63) * 16);          \
        oacc[0][j2] = mfma16(pf0, bv_, oacc[0][j2]);                             \
        oacc[1][j2] = mfma16(pf1, bv_, oacc[1][j2]);                             \
      }                                                                          \
    }                                                                            \
  } while (0)

  // One pipelined step: tile t uses CUR sacc; QK(t+1) fills NXT.
#define STEP(t, CUR, NXT) do {                                                   \
    WAITN0();                                                                    \
    __syncthreads();                                                             \
    if ((t) < 14) K_DMA((t) + 2);                                                \
    if ((t) < 15) V_DMA((t) + 1);                                                \
    if ((t) < 15) QK((t) + 1, NXT);                                              \
    EXPPV((t), CUR);                                                             \
  } while (0)

  f32x4 oacc[2][8] = {};
  f32x4 sA[4][2], sB[4][2];

  K_DMA(0);
  WAITN0();
  __syncthreads();                              // K(0) visible to all waves
  K_DMA(1); V_DMA(0);                           // land during QK(0)
  QK(0, sA);

  for (int tp = 0; tp < 8; ++tp) {
    STEP(2 * tp,     sA, sB);
    STEP(2 * tp + 1, sB, sA);
  }
#undef STEP
#undef EXPPV
#undef QK
#undef K_DMA
#undef V_DMA

  // max over this block's 128 q rows, per output column d
  for (int j2 = 0; j2 < 8; ++j2) {
    float m = -3.4e38f;
    for (int j = 0; j < 2; ++j)
      for (int rr = 0; rr < 4; ++rr)
        m = fmaxf(m, oacc[j][j2][rr]);
    m = fmaxf(m, __shfl_xor(m, 16, 64));
    m = fmaxf(m, __shfl_xor(m, 32, 64));
    if (lane < 16) redm[wave][j2 * 16 + ln] = m;
  }
  __syncthreads();
  if (tid < 128) {
    float m = fmaxf(fmaxf(redm[0][tid], redm[1][tid]), fmaxf(redm[2][tid], redm[3][tid]));
    // sign-aware integer atomic max (IEEE total order); out pre-init'd to -inf
    float* addr = out + (size_t)b * 128 + tid;
    if (m >= 0.0f) atomicMax((int*)addr, __float_as_int(m));
    else           atomicMin((unsigned int*)addr, __float_as_uint(m));
  }
}

// ============================================================================
extern "C" void kernel_launch(void* const* d_in, const int* in_sizes, int n_in,
                              void* d_out, int out_size, void* d_ws, size_t ws_size,
                              hipStream_t stream) {
  const float* q  = (const float*)d_in[0];
  const float* Wq = (const float*)d_in[1];
  const float* bq = (const float*)d_in[2];
  const float* Wk = (const float*)d_in[3];
  const float* bk = (const float*)d_in[4];
  const float* Wv = (const float*)d_in[5];
  const float* bv = (const float*)d_in[6];
  float* out = (float*)d_out;

  char* ws = (char*)d_ws;
  bf16*  Qb    = (bf16*)(ws);                         // 16 MB granule tiles [s][d]
  bf16*  Kb    = (bf16*)(ws + (16u << 20));           // 16 MB
  bf16*  VT    = (bf16*)(ws + (32u << 20));           // 16 MB (V^T, row-permuted)
  float* nlg   = (float*)(ws + (48u << 20));          // 256 KB [64][1024]  -log2(colsum)
  bf16*  Wc    = (bf16*)(ws + (49u << 20));           // 192 KB [3][32][128][8]

  k_prep <<<48,           256, 0, stream>>>(Wq, Wk, Wv, Wc, out);
  k_qkv  <<<dim3(1024),   256, 0, stream>>>(q, Wc, bq, bk, bv, Qb, Kb, VT);
  k_stats<<<dim3(64, 8),  256, 0, stream>>>(Qb, Kb, nlg);
  k_attn <<<dim3(64, 8),  256, 0, stream>>>(Qb, Kb, VT, nlg, out);
}